// Round 7
// baseline (118.045 us; speedup 1.0000x reference)
//
#include <hip/hip_runtime.h>

typedef __attribute__((ext_vector_type(8))) short short8;
typedef __attribute__((ext_vector_type(4))) float f32x4;

#define EPS   1e-3f
#define ALPHA 0.3f

#define MFMA(a, b, c) __builtin_amdgcn_mfma_f32_16x16x32_bf16((a), (b), (c), 0, 0, 0)

__device__ __forceinline__ unsigned short f2bf(float f) {
    unsigned u = __float_as_uint(f);
    unsigned r = u + 0x7FFFu + ((u >> 16) & 1u);
    return (unsigned short)(r >> 16);
}
__device__ __forceinline__ float lrelu(float v) { return v > 0.f ? v : ALPHA * v; }

// ---------------------------------------------------------------------------
// Shared M-phase: M[32 rows][100] = Hb(bf16 [32][264]) @ Wd[256][100] + bd.
// Stages Wd transposed (c-major) into WdT [112][264] bf16, then 14 MFMA tiles.
// Caller must __syncthreads() before (Hb complete, WdT alias region free).
// Mt layout: [10][1024][16] (k-slice-major for coalesced diversity staging).
// ---------------------------------------------------------------------------
__device__ __forceinline__ void m_phase(
    const unsigned short (*Hb)[264], unsigned short (*WdT)[264],
    const float* __restrict__ Wd, const float* __restrict__ bd,
    float* __restrict__ Mt, int xt, int t)
{
#pragma unroll 4
    for (int idx = t; idx < 112 * 256; idx += 256) {
        const int c = idx % 112;
        const int k = idx / 112;
        WdT[c][k] = (c < 100) ? f2bf(Wd[k * 100 + c]) : (unsigned short)0;
    }
    __syncthreads();

    const int lane = t & 63, w = t >> 6, r = lane & 15, g = lane >> 4;
    for (int tile = w; tile < 14; tile += 4) {
        const int rt = tile / 7, c7 = tile % 7;
        const unsigned short* Ap = &Hb[rt * 16 + r][g * 8];
        const unsigned short* Bp = &WdT[c7 * 16 + r][g * 8];
        f32x4 a0 = {0.f, 0.f, 0.f, 0.f}, a1 = {0.f, 0.f, 0.f, 0.f};
#pragma unroll
        for (int k0 = 0; k0 < 256; k0 += 64) {
            a0 = MFMA(*(const short8*)(Ap + k0),      *(const short8*)(Bp + k0),      a0);
            a1 = MFMA(*(const short8*)(Ap + k0 + 32), *(const short8*)(Bp + k0 + 32), a1);
        }
        const f32x4 acc = a0 + a1;
        const int c = c7 * 16 + r;
        if (c < 100) {
            const int kq = c / 10, d = c - kq * 10;
            const float bv = bd[c];
            float* dst = Mt + (size_t)kq * (1024 * 16)
                       + (size_t)(xt * 32 + rt * 16 + g * 4) * 16 + d;
#pragma unroll
            for (int i = 0; i < 4; ++i) dst[(size_t)i * 16] = acc[i] + bv;
        }
    }
}

// ---------------------------------------------------------------------------
// stage0: 32 blocks x 32 rows. h0 = x@W0 + b0 (on-the-fly W0 bf16 staging,
// double-buffered), then M0 = h0b @ Wd0 + bd0 in-block.
// ---------------------------------------------------------------------------
__global__ __launch_bounds__(256) void stage0_kernel(
    const float* __restrict__ x, const float* __restrict__ W0,
    const float* __restrict__ b0, const float* __restrict__ Wd0,
    const float* __restrict__ bd0,
    float* __restrict__ h0, float* __restrict__ Mt0)
{
    __shared__ __align__(16) char smem[116736];
    unsigned short (*At)[520]  = (unsigned short(*)[520])(smem);            // 33,280 B
    unsigned short (*BtA)[520] = (unsigned short(*)[520])(smem + 33280);    // 33,280 B
    unsigned short (*BtB)[520] = (unsigned short(*)[520])(smem + 66560);    // 33,280 B
    unsigned short (*Hb)[264]  = (unsigned short(*)[264])(smem + 99840);    // 16,896 B
    unsigned short (*WdT)[264] = (unsigned short(*)[264])(smem + 33280);    // alias Bt

    const int t = threadIdx.x, xt = blockIdx.x;
    const int lane = t & 63, w = t >> 6;

    // stage a 32-col tile of W0 (fp32 -> bf16 transposed) into B
    auto stageB = [&](int ct, unsigned short (*B)[520]) {
        const int kr = t >> 3, nf = t & 7;
#pragma unroll
        for (int rnd = 0; rnd < 16; ++rnd) {
            const int k = kr + rnd * 32;
            const float4 v = *(const float4*)&W0[(size_t)k * 256 + ct * 32 + nf * 4];
            B[nf * 4 + 0][k] = f2bf(v.x);
            B[nf * 4 + 1][k] = f2bf(v.y);
            B[nf * 4 + 2][k] = f2bf(v.z);
            B[nf * 4 + 3][k] = f2bf(v.w);
        }
    };

    stageB(0, BtA);

    // phase 1: x rows -> At bf16 [32][520]
    {
        const int row = t >> 3, kc = t & 7;
        const float* xp = x + (size_t)(xt * 32 + row) * 512 + kc * 64;
#pragma unroll
        for (int i = 0; i < 8; ++i) {
            const float4 lo = ((const float4*)xp)[i * 2];
            const float4 hi = ((const float4*)xp)[i * 2 + 1];
            short8 p;
            p[0] = f2bf(lo.x); p[1] = f2bf(lo.y); p[2] = f2bf(lo.z); p[3] = f2bf(lo.w);
            p[4] = f2bf(hi.x); p[5] = f2bf(hi.y); p[6] = f2bf(hi.z); p[7] = f2bf(hi.w);
            *(short8*)&At[row][kc * 64 + i * 8] = p;
        }
    }
    __syncthreads();

    // phase 2: h0 = At @ W0 col-tiles (double-buffered)
    const int wr = w >> 1, wn = w & 1, r = lane & 15, g = lane >> 4;
    for (int ct = 0; ct < 8; ++ct) {
        unsigned short (*Bcur)[520] = (ct & 1) ? BtB : BtA;
        if (ct < 7) stageB(ct + 1, (ct & 1) ? BtA : BtB);

        const unsigned short* Ap = &At[wr * 16 + r][g * 8];
        const unsigned short* Bp = &Bcur[wn * 16 + r][g * 8];
        f32x4 a0 = {0.f, 0.f, 0.f, 0.f}, a1 = {0.f, 0.f, 0.f, 0.f};
#pragma unroll
        for (int k0 = 0; k0 < 512; k0 += 64) {
            a0 = MFMA(*(const short8*)(Ap + k0),      *(const short8*)(Bp + k0),      a0);
            a1 = MFMA(*(const short8*)(Ap + k0 + 32), *(const short8*)(Bp + k0 + 32), a1);
        }
        const f32x4 acc = a0 + a1;
        const int bcol = ct * 32 + wn * 16 + r;
        const float bv = b0[bcol];
        const int orow = xt * 32 + wr * 16 + g * 4;
        const int lrow = wr * 16 + g * 4;
#pragma unroll
        for (int i = 0; i < 4; ++i) {
            const float hv = acc[i] + bv;
            h0[(size_t)(orow + i) * 256 + bcol] = hv;
            Hb[lrow + i][bcol] = f2bf(hv);
        }
        __syncthreads();
    }

    // phase 3: M0 = Hb @ Wd0 + bd0
    m_phase(Hb, WdT, Wd0, bd0, Mt0, xt, t);
}

// ---------------------------------------------------------------------------
// stage1: 32 blocks x 32 rows. LN0(+beta,+lrelu) once per row -> At bf16
// [32][296] (K=288 padded); h1 = At@W1 + b1 (on-the-fly W1 staging);
// M1 = h1b @ Wd1 + bd1.
// ---------------------------------------------------------------------------
__global__ __launch_bounds__(256) void stage1_kernel(
    const float* __restrict__ h0, const float* __restrict__ div0,
    const float* __restrict__ beta0,
    const float* __restrict__ W1, const float* __restrict__ b1,
    const float* __restrict__ Wd1, const float* __restrict__ bd1,
    float* __restrict__ h1, float* __restrict__ Mt1)
{
    __shared__ __align__(16) char smem[94976];
    unsigned short (*At)[296]  = (unsigned short(*)[296])(smem);            // 18,944 B
    unsigned short (*Hb)[264]  = (unsigned short(*)[264])(smem + 18944);    // 16,896 B
    unsigned short (*BtA)[296] = (unsigned short(*)[296])(smem + 35840);    // 18,944 B
    unsigned short (*BtB)[296] = (unsigned short(*)[296])(smem + 54784);    // 18,944 B
    unsigned short (*WdT)[264] = (unsigned short(*)[264])(smem + 35840);    // alias Bt

    const int t = threadIdx.x, xt = blockIdx.x;
    const int lane = t & 63, w = t >> 6;

    // stage a 32-col tile of W1 (rows k<266 real, 266..287 zero)
    auto stageB = [&](int ct, unsigned short (*B)[296]) {
        const int kr = t >> 3, nf = t & 7;
#pragma unroll
        for (int rnd = 0; rnd < 9; ++rnd) {
            const int k = kr + rnd * 32;
            float4 v = make_float4(0.f, 0.f, 0.f, 0.f);
            if (k < 266) v = *(const float4*)&W1[(size_t)k * 256 + ct * 32 + nf * 4];
            B[nf * 4 + 0][k] = f2bf(v.x);
            B[nf * 4 + 1][k] = f2bf(v.y);
            B[nf * 4 + 2][k] = f2bf(v.z);
            B[nf * 4 + 3][k] = f2bf(v.w);
        }
    };

    stageB(0, BtA);   // overlap W1 load latency with LN compute

    // phase 0: LN0 per row (wave w owns rows w*8..w*8+7)
    for (int rr = 0; rr < 8; ++rr) {
        const int row = xt * 32 + w * 8 + rr;
        const float4 hv = ((const float4*)(h0 + (size_t)row * 256))[lane];
        const float dvv = (lane < 10) ? div0[(size_t)row * 10 + lane] : 0.f;
        float s = hv.x + hv.y + hv.z + hv.w + dvv;
        float q = hv.x * hv.x + hv.y * hv.y + hv.z * hv.z + hv.w * hv.w + dvv * dvv;
#pragma unroll
        for (int m = 32; m > 0; m >>= 1) { s += __shfl_xor(s, m); q += __shfl_xor(q, m); }
        const float mean = s * (1.f / 266.f);
        const float var  = q * (1.f / 266.f) - mean * mean;
        const float inv  = rsqrtf(var + EPS);
        const int lr = w * 8 + rr;
        const float4 b4 = ((const float4*)beta0)[lane];
        ushort4 o;
        o.x = f2bf(lrelu((hv.x - mean) * inv + b4.x));
        o.y = f2bf(lrelu((hv.y - mean) * inv + b4.y));
        o.z = f2bf(lrelu((hv.z - mean) * inv + b4.z));
        o.w = f2bf(lrelu((hv.w - mean) * inv + b4.w));
        *(ushort4*)&At[lr][lane * 4] = o;
        if (lane < 10)
            At[lr][256 + lane] = f2bf(lrelu((dvv - mean) * inv + beta0[256 + lane]));
        else if (lane < 40)
            At[lr][256 + lane] = 0;   // cols 266..295 zero
    }
    __syncthreads();

    // phase 2: h1 = At @ W1 col-tiles (double-buffered), K=288
    const int wr = w >> 1, wn = w & 1, r = lane & 15, g = lane >> 4;
    for (int ct = 0; ct < 8; ++ct) {
        unsigned short (*Bcur)[296] = (ct & 1) ? BtB : BtA;
        if (ct < 7) stageB(ct + 1, (ct & 1) ? BtA : BtB);

        const unsigned short* Ap = &At[wr * 16 + r][g * 8];
        const unsigned short* Bp = &Bcur[wn * 16 + r][g * 8];
        f32x4 a0 = {0.f, 0.f, 0.f, 0.f}, a1 = {0.f, 0.f, 0.f, 0.f};
#pragma unroll
        for (int k0 = 0; k0 < 256; k0 += 64) {
            a0 = MFMA(*(const short8*)(Ap + k0),      *(const short8*)(Bp + k0),      a0);
            a1 = MFMA(*(const short8*)(Ap + k0 + 32), *(const short8*)(Bp + k0 + 32), a1);
        }
        a0 = MFMA(*(const short8*)(Ap + 256), *(const short8*)(Bp + 256), a0);
        const f32x4 acc = a0 + a1;
        const int bcol = ct * 32 + wn * 16 + r;
        const float bv = b1[bcol];
        const int orow = xt * 32 + wr * 16 + g * 4;
        const int lrow = wr * 16 + g * 4;
#pragma unroll
        for (int i = 0; i < 4; ++i) {
            const float hv = acc[i] + bv;
            h1[(size_t)(orow + i) * 256 + bcol] = hv;
            Hb[lrow + i][bcol] = f2bf(hv);
        }
        __syncthreads();
    }

    // phase 3: M1 = Hb @ Wd1 + bd1
    m_phase(Hb, WdT, Wd1, bd1, Mt1, xt, t);
}

// ---------------------------------------------------------------------------
// diversity: grid (32,10). Mt slice [1024][16] staged fully coalesced.
// ---------------------------------------------------------------------------
__global__ __launch_bounds__(256) void diversity_kernel(
    const float* __restrict__ Mt, float* __restrict__ divOut)
{
    __shared__ float Ms[1024 * 16];
    __shared__ float red[256];

    const int t = threadIdx.x;
    const float* src = Mt + (size_t)blockIdx.y * (1024 * 16);
    for (int i = t; i < 1024 * 4; i += 256)
        ((float4*)Ms)[i] = ((const float4*)src)[i];
    __syncthreads();

    const int il = t & 31, jc = t >> 5;
    const int i = blockIdx.x * 32 + il;

    const float4 m0 = *(const float4*)&Ms[i * 16];
    const float4 m1 = *(const float4*)&Ms[i * 16 + 4];
    const float4 m2 = *(const float4*)&Ms[i * 16 + 8];

    float acc = 0.f;
    const int jB = jc * 128;
#pragma unroll 2
    for (int j = jB; j < jB + 128; ++j) {
        const float4 v0 = *(const float4*)&Ms[j * 16];
        const float4 v1 = *(const float4*)&Ms[j * 16 + 4];
        const float4 v2 = *(const float4*)&Ms[j * 16 + 8];
        float l1 = fabsf(m0.x - v0.x) + fabsf(m0.y - v0.y)
                 + fabsf(m0.z - v0.z) + fabsf(m0.w - v0.w)
                 + fabsf(m1.x - v1.x) + fabsf(m1.y - v1.y)
                 + fabsf(m1.z - v1.z) + fabsf(m1.w - v1.w)
                 + fabsf(m2.x - v2.x) + fabsf(m2.y - v2.y);
        acc += __expf(-l1);
    }

    red[t] = acc;
    __syncthreads();
    if (t < 32) {
        float s = 0.f;
#pragma unroll
        for (int c = 0; c < 8; ++c) s += red[c * 32 + t];
        divOut[(size_t)(blockIdx.x * 32 + t) * 10 + blockIdx.y] = s;
    }
}

// ---------------------------------------------------------------------------
// ln_final: 256 blocks x 4 waves; one row per wave. LN + lrelu + dot(Wf)+bf.
// ---------------------------------------------------------------------------
__global__ __launch_bounds__(256) void ln_final(
    const float* __restrict__ h1, const float* __restrict__ div1,
    const float* __restrict__ beta1, const float* __restrict__ Wf,
    const float* __restrict__ bf, float* __restrict__ out)
{
    const int t = threadIdx.x, lane = t & 63;
    const int row = blockIdx.x * 4 + (t >> 6);

    const float4 hv = ((const float4*)(h1 + (size_t)row * 256))[lane];
    const float dv = (lane < 10) ? div1[(size_t)row * 10 + lane] : 0.f;

    float s = hv.x + hv.y + hv.z + hv.w + dv;
    float q = hv.x * hv.x + hv.y * hv.y + hv.z * hv.z + hv.w * hv.w + dv * dv;
#pragma unroll
    for (int m = 32; m > 0; m >>= 1) { s += __shfl_xor(s, m); q += __shfl_xor(q, m); }

    const float mean = s * (1.f / 266.f);
    const float var  = q * (1.f / 266.f) - mean * mean;
    const float inv  = rsqrtf(var + EPS);

    const float4 bv = ((const float4*)beta1)[lane];
    const float4 wf = ((const float4*)Wf)[lane];
    float d = lrelu((hv.x - mean) * inv + bv.x) * wf.x
            + lrelu((hv.y - mean) * inv + bv.y) * wf.y
            + lrelu((hv.z - mean) * inv + bv.z) * wf.z
            + lrelu((hv.w - mean) * inv + bv.w) * wf.w;
    if (lane < 10)
        d += lrelu((dv - mean) * inv + beta1[256 + lane]) * Wf[256 + lane];
#pragma unroll
    for (int m = 32; m > 0; m >>= 1) d += __shfl_xor(d, m);
    if (lane == 0) out[row] = d + bf[0];
}

// ---------------------------------------------------------------------------
extern "C" void kernel_launch(void* const* d_in, const int* in_sizes, int n_in,
                              void* d_out, int out_size, void* d_ws, size_t ws_size,
                              hipStream_t stream)
{
    const float* x     = (const float*)d_in[0];
    const float* W0    = (const float*)d_in[1];
    const float* b0    = (const float*)d_in[2];
    const float* Wd0   = (const float*)d_in[3];
    const float* bd0   = (const float*)d_in[4];
    const float* beta0 = (const float*)d_in[5];
    const float* W1    = (const float*)d_in[6];
    const float* b1    = (const float*)d_in[7];
    const float* Wd1   = (const float*)d_in[8];
    const float* bd1   = (const float*)d_in[9];
    const float* beta1 = (const float*)d_in[10];
    const float* Wf    = (const float*)d_in[11];
    const float* bf    = (const float*)d_in[12];
    float* out = (float*)d_out;

    float* fws = (float*)d_ws;
    float* h0   = fws;                      // 1024*256
    float* h1   = h0 + 1024 * 256;          // 1024*256
    float* Mt0  = h1 + 1024 * 256;          // 10*1024*16
    float* Mt1  = Mt0 + 10 * 1024 * 16;     // 10*1024*16
    float* div0 = Mt1 + 10 * 1024 * 16;     // 1024*10
    float* div1 = div0 + 1024 * 10;         // 1024*10

    dim3 blk(256);

    stage0_kernel<<<dim3(32), blk, 0, stream>>>(x, W0, b0, Wd0, bd0, h0, Mt0);

    diversity_kernel<<<dim3(32, 10), blk, 0, stream>>>(Mt0, div0);

    stage1_kernel<<<dim3(32), blk, 0, stream>>>(
        h0, div0, beta0, W1, b1, Wd1, bd1, h1, Mt1);

    diversity_kernel<<<dim3(32, 10), blk, 0, stream>>>(Mt1, div1);

    ln_final<<<dim3(256), blk, 0, stream>>>(h1, div1, beta1, Wf, bf, out);
}

// Round 8
// 81.040 us; speedup vs baseline: 1.4566x; 1.4566x over previous
//
#include <hip/hip_runtime.h>

typedef __attribute__((ext_vector_type(8))) short short8;
typedef __attribute__((ext_vector_type(4))) float f32x4;

#define EPS   1e-3f
#define ALPHA 0.3f

#define MFMA(a, b, c) __builtin_amdgcn_mfma_f32_16x16x32_bf16((a), (b), (c), 0, 0, 0)

__device__ __forceinline__ unsigned short f2bf(float f) {
    unsigned u = __float_as_uint(f);
    unsigned r = u + 0x7FFFu + ((u >> 16) & 1u);
    return (unsigned short)(r >> 16);
}
__device__ __forceinline__ float lrelu(float v) { return v > 0.f ? v : ALPHA * v; }

// ---------------------------------------------------------------------------
// N1: h0 = x@W0 + b0. grid (32 xt, 8 yt) = 256 blocks, 32x32 tile each.
// Writes h0 (fp32, for LN) and h0b (bf16, for divM). yt==0 blocks also zero
// div0/div1 (they are atomic accumulators, must be zeroed EVERY call).
// ---------------------------------------------------------------------------
__global__ __launch_bounds__(256) void h0_kernel(
    const float* __restrict__ x, const float* __restrict__ W0,
    const float* __restrict__ b0,
    float* __restrict__ h0, unsigned short* __restrict__ h0b,
    float* __restrict__ div0, float* __restrict__ div1)
{
    __shared__ unsigned short At[32][520];
    __shared__ unsigned short Bt[32][520];

    const int t = threadIdx.x, xt = blockIdx.x, yt = blockIdx.y;

    // A stage: x rows -> bf16
    {
        const int row = t >> 3, kc = t & 7;
        const float* xp = x + (size_t)(xt * 32 + row) * 512 + kc * 64;
#pragma unroll
        for (int i = 0; i < 8; ++i) {
            const float4 lo = ((const float4*)xp)[i * 2];
            const float4 hi = ((const float4*)xp)[i * 2 + 1];
            short8 p;
            p[0] = f2bf(lo.x); p[1] = f2bf(lo.y); p[2] = f2bf(lo.z); p[3] = f2bf(lo.w);
            p[4] = f2bf(hi.x); p[5] = f2bf(hi.y); p[6] = f2bf(hi.z); p[7] = f2bf(hi.w);
            *(short8*)&At[row][kc * 64 + i * 8] = p;
        }
    }
    // B stage: W0 col-tile transposed (float4 over cols)
    {
        const int kr = t >> 3, nf = t & 7;
#pragma unroll
        for (int rnd = 0; rnd < 16; ++rnd) {
            const int k = kr + rnd * 32;
            const float4 v = *(const float4*)&W0[(size_t)k * 256 + yt * 32 + nf * 4];
            Bt[nf * 4 + 0][k] = f2bf(v.x);
            Bt[nf * 4 + 1][k] = f2bf(v.y);
            Bt[nf * 4 + 2][k] = f2bf(v.z);
            Bt[nf * 4 + 3][k] = f2bf(v.w);
        }
    }
    __syncthreads();

    const int lane = t & 63, w = t >> 6;
    const int wr = w >> 1, wn = w & 1, r = lane & 15, g = lane >> 4;
    const unsigned short* Ap = &At[wr * 16 + r][g * 8];
    const unsigned short* Bp = &Bt[wn * 16 + r][g * 8];
    f32x4 a0 = {0.f, 0.f, 0.f, 0.f}, a1 = {0.f, 0.f, 0.f, 0.f};
#pragma unroll
    for (int k0 = 0; k0 < 512; k0 += 64) {
        a0 = MFMA(*(const short8*)(Ap + k0),      *(const short8*)(Bp + k0),      a0);
        a1 = MFMA(*(const short8*)(Ap + k0 + 32), *(const short8*)(Bp + k0 + 32), a1);
    }
    const f32x4 acc = a0 + a1;
    const int bcol = yt * 32 + wn * 16 + r;
    const float bv = b0[bcol];
    const int orow = xt * 32 + wr * 16 + g * 4;
#pragma unroll
    for (int i = 0; i < 4; ++i) {
        const float hv = acc[i] + bv;
        h0[(size_t)(orow + i) * 256 + bcol]  = hv;
        h0b[(size_t)(orow + i) * 256 + bcol] = f2bf(hv);
    }

    if (yt == 0) {
        for (int i = t; i < 320; i += 256) {
            div0[xt * 320 + i] = 0.f;
            div1[xt * 320 + i] = 0.f;
        }
    }
}

// ---------------------------------------------------------------------------
// N2/N4: divM. grid (64, 10): bx -> (it = bx>>3, jt = bx&7), k = by.
// Per block: build M-tiles for the i-range and j-range (128 rows each) from
// Hb (bf16 h) @ Wd cols [k*10..k*10+10) + bd, entirely in-LDS via MFMA.
// Then 128x128 pair loop: acc_i += exp(-L1(Mi,Mj)); one atomicAdd per (i,k).
// LDS ~60 KB -> 2 blocks/CU.
// ---------------------------------------------------------------------------
__global__ __launch_bounds__(256) void divm_kernel(
    const unsigned short* __restrict__ Hb, const float* __restrict__ Wd,
    const float* __restrict__ bd, float* __restrict__ divOut)
{
    __shared__ unsigned short Ab[64][264];
    __shared__ unsigned short WdT[16][264];
    __shared__ float Ms[2][128][16];
    __shared__ float red[256];

    const int t = threadIdx.x;
    const int it = blockIdx.x >> 3, jt = blockIdx.x & 7;
    const int k = blockIdx.y;

    // WdT: Wd cols [k*10, +10) transposed, 16-padded (pad cols zero)
    {
        const int c = t & 15, kb = t >> 4;
#pragma unroll
        for (int kk = 0; kk < 16; ++kk) {
            const int kidx = kb * 16 + kk;
            WdT[c][kidx] = (c < 10) ? f2bf(Wd[(size_t)kidx * 100 + k * 10 + c])
                                    : (unsigned short)0;
        }
    }

    const int lane = t & 63, w = t >> 6, r = lane & 15, g = lane >> 4;
    const bool diag = (it == jt);
    const int nsides = diag ? 1 : 2;

    for (int s = 0; s < nsides; ++s) {
        const int rows0 = (s ? jt : it) * 128;
        for (int c2 = 0; c2 < 2; ++c2) {
            __syncthreads();   // previous Ab readers done
            {
                const int row = t >> 2, qc = t & 3;
                const unsigned short* src =
                    Hb + (size_t)(rows0 + c2 * 64 + row) * 256 + qc * 64;
#pragma unroll
                for (int i = 0; i < 8; ++i)
                    *(short8*)&Ab[row][qc * 64 + i * 8] = ((const short8*)src)[i];
            }
            __syncthreads();
            // wave w computes 16-row tile w of this 64-row chunk
            const unsigned short* Ap = &Ab[w * 16 + r][g * 8];
            const unsigned short* Bp = &WdT[r][g * 8];
            f32x4 a0 = {0.f, 0.f, 0.f, 0.f}, a1 = {0.f, 0.f, 0.f, 0.f};
#pragma unroll
            for (int k0 = 0; k0 < 256; k0 += 64) {
                a0 = MFMA(*(const short8*)(Ap + k0),      *(const short8*)(Bp + k0),      a0);
                a1 = MFMA(*(const short8*)(Ap + k0 + 32), *(const short8*)(Bp + k0 + 32), a1);
            }
            const f32x4 acc = a0 + a1;
            const float bv = (r < 10) ? bd[k * 10 + r] : 0.f;
            const int rowbase = c2 * 64 + w * 16 + g * 4;
#pragma unroll
            for (int i = 0; i < 4; ++i)
                Ms[s][rowbase + i][r] = acc[i] + bv;
        }
    }
    __syncthreads();

    // pair loop: thread = (il = t&127, jh = t>>7)
    const int il = t & 127, jh = t >> 7;
    const int sj = diag ? 0 : 1;
    const float4 m0 = *(const float4*)&Ms[0][il][0];
    const float4 m1 = *(const float4*)&Ms[0][il][4];
    const float2 m2 = *(const float2*)&Ms[0][il][8];

    float acc = 0.f;
    const int jB = jh * 64;
#pragma unroll 2
    for (int j = jB; j < jB + 64; ++j) {
        const float4 v0 = *(const float4*)&Ms[sj][j][0];
        const float4 v1 = *(const float4*)&Ms[sj][j][4];
        const float2 v2 = *(const float2*)&Ms[sj][j][8];
        float l1 = fabsf(m0.x - v0.x) + fabsf(m0.y - v0.y)
                 + fabsf(m0.z - v0.z) + fabsf(m0.w - v0.w)
                 + fabsf(m1.x - v1.x) + fabsf(m1.y - v1.y)
                 + fabsf(m1.z - v1.z) + fabsf(m1.w - v1.w)
                 + fabsf(m2.x - v2.x) + fabsf(m2.y - v2.y);
        acc += __expf(-l1);
    }

    red[t] = acc;
    __syncthreads();
    if (t < 128)
        atomicAdd(&divOut[(size_t)(it * 128 + t) * 10 + k], red[t] + red[t + 128]);
}

// ---------------------------------------------------------------------------
// N3: LN0 (fused, x8 redundant per xt) + h1 = a0@W1 + b1. grid (32, 8).
// Writes h1 (fp32) and h1b (bf16).
// ---------------------------------------------------------------------------
__global__ __launch_bounds__(256) void h1_kernel(
    const float* __restrict__ h0, const float* __restrict__ div0,
    const float* __restrict__ beta0,
    const float* __restrict__ W1, const float* __restrict__ b1,
    float* __restrict__ h1, unsigned short* __restrict__ h1b)
{
    __shared__ unsigned short At[32][296];
    __shared__ unsigned short Bt[32][296];

    const int t = threadIdx.x, xt = blockIdx.x, yt = blockIdx.y;
    const int lane = t & 63, w = t >> 6;

    // B stage: W1 col-tile transposed, k >= 266 zero (K padded to 288)
    {
        const int kr = t >> 3, nf = t & 7;
#pragma unroll
        for (int rnd = 0; rnd < 9; ++rnd) {
            const int k = kr + rnd * 32;
            float4 v = make_float4(0.f, 0.f, 0.f, 0.f);
            if (k < 266) v = *(const float4*)&W1[(size_t)k * 256 + yt * 32 + nf * 4];
            Bt[nf * 4 + 0][k] = f2bf(v.x);
            Bt[nf * 4 + 1][k] = f2bf(v.y);
            Bt[nf * 4 + 2][k] = f2bf(v.z);
            Bt[nf * 4 + 3][k] = f2bf(v.w);
        }
    }

    // LN0: wave w handles rows w*8 .. w*8+7
    for (int rr = 0; rr < 8; ++rr) {
        const int row = xt * 32 + w * 8 + rr;
        const float4 hv = ((const float4*)(h0 + (size_t)row * 256))[lane];
        const float dvv = (lane < 10) ? div0[(size_t)row * 10 + lane] : 0.f;
        float s = hv.x + hv.y + hv.z + hv.w + dvv;
        float q = hv.x * hv.x + hv.y * hv.y + hv.z * hv.z + hv.w * hv.w + dvv * dvv;
#pragma unroll
        for (int m = 32; m > 0; m >>= 1) { s += __shfl_xor(s, m); q += __shfl_xor(q, m); }
        const float mean = s * (1.f / 266.f);
        const float var  = q * (1.f / 266.f) - mean * mean;
        const float inv  = rsqrtf(var + EPS);
        const int lr = w * 8 + rr;
        const float4 b4 = ((const float4*)beta0)[lane];
        ushort4 o;
        o.x = f2bf(lrelu((hv.x - mean) * inv + b4.x));
        o.y = f2bf(lrelu((hv.y - mean) * inv + b4.y));
        o.z = f2bf(lrelu((hv.z - mean) * inv + b4.z));
        o.w = f2bf(lrelu((hv.w - mean) * inv + b4.w));
        *(ushort4*)&At[lr][lane * 4] = o;
        if (lane < 10)
            At[lr][256 + lane] = f2bf(lrelu((dvv - mean) * inv + beta0[256 + lane]));
        else if (lane < 40)
            At[lr][256 + lane] = 0;   // pad 266..295
    }
    __syncthreads();

    // MFMA K=288
    const int wr = w >> 1, wn = w & 1, r = lane & 15, g = lane >> 4;
    const unsigned short* Ap = &At[wr * 16 + r][g * 8];
    const unsigned short* Bp = &Bt[wn * 16 + r][g * 8];
    f32x4 a0 = {0.f, 0.f, 0.f, 0.f}, a1 = {0.f, 0.f, 0.f, 0.f};
#pragma unroll
    for (int k0 = 0; k0 < 256; k0 += 64) {
        a0 = MFMA(*(const short8*)(Ap + k0),      *(const short8*)(Bp + k0),      a0);
        a1 = MFMA(*(const short8*)(Ap + k0 + 32), *(const short8*)(Bp + k0 + 32), a1);
    }
    a0 = MFMA(*(const short8*)(Ap + 256), *(const short8*)(Bp + 256), a0);
    const f32x4 acc = a0 + a1;
    const int bcol = yt * 32 + wn * 16 + r;
    const float bv = b1[bcol];
    const int orow = xt * 32 + wr * 16 + g * 4;
#pragma unroll
    for (int i = 0; i < 4; ++i) {
        const float hv = acc[i] + bv;
        h1[(size_t)(orow + i) * 256 + bcol]  = hv;
        h1b[(size_t)(orow + i) * 256 + bcol] = f2bf(hv);
    }
}

// ---------------------------------------------------------------------------
// N5: LN1 + LeakyReLU + dot(Wf) + bf. 256 blocks x 4 waves, one row per wave.
// ---------------------------------------------------------------------------
__global__ __launch_bounds__(256) void ln_final(
    const float* __restrict__ h1, const float* __restrict__ div1,
    const float* __restrict__ beta1, const float* __restrict__ Wf,
    const float* __restrict__ bf, float* __restrict__ out)
{
    const int t = threadIdx.x, lane = t & 63;
    const int row = blockIdx.x * 4 + (t >> 6);

    const float4 hv = ((const float4*)(h1 + (size_t)row * 256))[lane];
    const float dv = (lane < 10) ? div1[(size_t)row * 10 + lane] : 0.f;

    float s = hv.x + hv.y + hv.z + hv.w + dv;
    float q = hv.x * hv.x + hv.y * hv.y + hv.z * hv.z + hv.w * hv.w + dv * dv;
#pragma unroll
    for (int m = 32; m > 0; m >>= 1) { s += __shfl_xor(s, m); q += __shfl_xor(q, m); }

    const float mean = s * (1.f / 266.f);
    const float var  = q * (1.f / 266.f) - mean * mean;
    const float inv  = rsqrtf(var + EPS);

    const float4 bv = ((const float4*)beta1)[lane];
    const float4 wf = ((const float4*)Wf)[lane];
    float d = lrelu((hv.x - mean) * inv + bv.x) * wf.x
            + lrelu((hv.y - mean) * inv + bv.y) * wf.y
            + lrelu((hv.z - mean) * inv + bv.z) * wf.z
            + lrelu((hv.w - mean) * inv + bv.w) * wf.w;
    if (lane < 10)
        d += lrelu((dv - mean) * inv + beta1[256 + lane]) * Wf[256 + lane];
#pragma unroll
    for (int m = 32; m > 0; m >>= 1) d += __shfl_xor(d, m);
    if (lane == 0) out[row] = d + bf[0];
}

// ---------------------------------------------------------------------------
extern "C" void kernel_launch(void* const* d_in, const int* in_sizes, int n_in,
                              void* d_out, int out_size, void* d_ws, size_t ws_size,
                              hipStream_t stream)
{
    const float* x     = (const float*)d_in[0];
    const float* W0    = (const float*)d_in[1];
    const float* b0    = (const float*)d_in[2];
    const float* Wd0   = (const float*)d_in[3];
    const float* bd0   = (const float*)d_in[4];
    const float* beta0 = (const float*)d_in[5];
    const float* W1    = (const float*)d_in[6];
    const float* b1    = (const float*)d_in[7];
    const float* Wd1   = (const float*)d_in[8];
    const float* bd1   = (const float*)d_in[9];
    const float* beta1 = (const float*)d_in[10];
    const float* Wf    = (const float*)d_in[11];
    const float* bf    = (const float*)d_in[12];
    float* out = (float*)d_out;

    float* fws = (float*)d_ws;
    float* h0   = fws;                      // 1024*256 fp32
    float* h1   = h0 + 1024 * 256;          // 1024*256 fp32
    float* div0 = h1 + 1024 * 256;          // 1024*10
    float* div1 = div0 + 1024 * 10;         // 1024*10
    unsigned short* h0b = (unsigned short*)(div1 + 1024 * 10);  // 1024*256 bf16
    unsigned short* h1b = h0b + 1024 * 256;                     // 1024*256 bf16

    dim3 blk(256);

    // N1: h0 (+ zero the div accumulators for this call)
    h0_kernel<<<dim3(32, 8), blk, 0, stream>>>(x, W0, b0, h0, h0b, div0, div1);

    // N2: M0 + diversity 0 (atomic accumulate into div0)
    divm_kernel<<<dim3(64, 10), blk, 0, stream>>>(h0b, Wd0, bd0, div0);

    // N3: LN0 (fused) + h1
    h1_kernel<<<dim3(32, 8), blk, 0, stream>>>(h0, div0, beta0, W1, b1, h1, h1b);

    // N4: M1 + diversity 1
    divm_kernel<<<dim3(64, 10), blk, 0, stream>>>(h1b, Wd1, bd1, div1);

    // N5: LN1 + head
    ln_final<<<dim3(256), blk, 0, stream>>>(h1, div1, beta1, Wf, bf, out);
}